// Round 2
// baseline (41686.368 us; speedup 1.0000x reference)
//
#include <hip/hip_runtime.h>
#include <cstdint>
#include <cstddef>

#define ZONEOUT 0.1f

typedef __attribute__((ext_vector_type(8))) short bf16x8;
typedef __attribute__((ext_vector_type(4))) float f32x4;
typedef __attribute__((ext_vector_type(4))) unsigned short u16x4;
typedef __attribute__((ext_vector_type(8))) unsigned short u16x8;
typedef __attribute__((ext_vector_type(4))) float float4_;

static constexpr int BB = 16;    // batch
static constexpr int TT = 4096;  // time
static constexpr int DD = 256;   // model dim
static constexpr int UU = 256;   // units
static constexpr int GG = 768;   // 3*UU
static constexpr int STR = 280;  // u16 row stride for 256-col LDS tiles (140 dw -> 2-way banks, free)

__device__ __forceinline__ unsigned short f2bf(float f) {
  unsigned int u = __builtin_bit_cast(unsigned int, f);
  u = u + 0x7fffu + ((u >> 16) & 1u);
  return (unsigned short)(u >> 16);
}
__device__ __forceinline__ float bf2f(unsigned short s) {
  unsigned int u = ((unsigned int)s) << 16;
  return __builtin_bit_cast(float, u);
}
__device__ __forceinline__ float sigm(float x) {
  float e = __builtin_amdgcn_exp2f(-1.4426950408889634f * x);
  return __builtin_amdgcn_rcpf(1.0f + e);
}
__device__ __forceinline__ float tanh_(float x) {
  float e = __builtin_amdgcn_exp2f(2.8853900817779268f * x);
  return 1.0f - 2.0f * __builtin_amdgcn_rcpf(1.0f + e);
}

// dst[n*K + k] = (bf16) src[k*N + n]   (src: [K][N] fp32, dst: [N][K] bf16)
__global__ void transpose_cast_kernel(const float* __restrict__ src,
                                      unsigned short* __restrict__ dst,
                                      int K, int N) {
  int idx = blockIdx.x * blockDim.x + threadIdx.x;
  int total = K * N;
  if (idx < total) {
    int k = idx / N, n = idx - k * N;          // read-coalesced
    dst[(size_t)n * K + k] = f2bf(src[idx]);
  }
}

// xg[m][u][slot] = (In @ W)[m][g] + b_in[g];  g = slot*256 + u.  64x64 tile.
__launch_bounds__(256, 2)
__global__ void gates_gemm_kernel(const float* __restrict__ In,          // [M][256] fp32
                                  const unsigned short* __restrict__ Wt, // [768][256] bf16 (transposed)
                                  const float* __restrict__ bin,         // [768]
                                  unsigned short* __restrict__ xgp) {    // [M][256][4] bf16
  __shared__ unsigned short Asm[64 * STR];
  __shared__ unsigned short Bsm[64 * STR];
  const int m0 = blockIdx.x * 64;
  const int n0 = blockIdx.y * 64;
  const int tid = threadIdx.x;
  {
    int row = tid >> 2, cb = (tid & 3) * 64;
    const float* src = In + (size_t)(m0 + row) * DD + cb;
#pragma unroll
    for (int i = 0; i < 16; ++i) {
      float4_ v = *(const float4_*)(src + i * 4);
      u16x4 o;
      o.x = f2bf(v.x); o.y = f2bf(v.y); o.z = f2bf(v.z); o.w = f2bf(v.w);
      *(u16x4*)(&Asm[row * STR + cb + i * 4]) = o;
    }
  }
  {
#pragma unroll
    for (int i = 0; i < 8; ++i) {
      int c = i * 256 + tid;
      int row = c >> 5, part = c & 31;
      u16x8 v = *(const u16x8*)(Wt + (size_t)(n0 + row) * 256 + part * 8);
      *(u16x8*)(&Bsm[row * STR + part * 8]) = v;
    }
  }
  __syncthreads();
  const int w = tid >> 6, l = tid & 63, lr = l & 15, lg = l >> 4;
  f32x4 acc[4] = {};
#pragma unroll
  for (int k0 = 0; k0 < 8; ++k0) {
    bf16x8 a = *(const bf16x8*)(&Asm[(16 * w + lr) * STR + 32 * k0 + 8 * lg]);
#pragma unroll
    for (int ti = 0; ti < 4; ++ti) {
      bf16x8 b = *(const bf16x8*)(&Bsm[(16 * ti + lr) * STR + 32 * k0 + 8 * lg]);
      acc[ti] = __builtin_amdgcn_mfma_f32_16x16x32_bf16(a, b, acc[ti], 0, 0, 0);
    }
  }
#pragma unroll
  for (int ti = 0; ti < 4; ++ti) {
    int gcol = n0 + 16 * ti + lr;
    float bias = bin[gcol];
    int u = gcol & 255, slot = gcol >> 8;
#pragma unroll
    for (int r = 0; r < 4; ++r) {
      int m = m0 + 16 * w + 4 * lg + r;
      xgp[(size_t)m * 1024 + u * 4 + slot] = f2bf(acc[ti][r] + bias);
    }
  }
}

// In-place dense head: y[m][:] = (bf16)y[m][:] @ Wd + bd.  64-row blocks, BN=256.
__launch_bounds__(256, 2)
__global__ void head_gemm_kernel(float* __restrict__ y,                   // [M][256] fp32, in-place
                                 const unsigned short* __restrict__ Wdt,  // [256][256] bf16 (transposed)
                                 const float* __restrict__ bd) {          // [256]
  __shared__ unsigned short Asm[64 * STR];
  const int m0 = blockIdx.x * 64;
  const int tid = threadIdx.x;
  {
    int row = tid >> 2, cb = (tid & 3) * 64;
    const float* src = y + (size_t)(m0 + row) * UU + cb;
#pragma unroll
    for (int i = 0; i < 16; ++i) {
      float4_ v = *(const float4_*)(src + i * 4);
      u16x4 o;
      o.x = f2bf(v.x); o.y = f2bf(v.y); o.z = f2bf(v.z); o.w = f2bf(v.w);
      *(u16x4*)(&Asm[row * STR + cb + i * 4]) = o;
    }
  }
  __syncthreads();
  const int w = tid >> 6, l = tid & 63, lr = l & 15, lg = l >> 4;
  f32x4 acc[16] = {};
#pragma unroll
  for (int k0 = 0; k0 < 8; ++k0) {
    bf16x8 a = *(const bf16x8*)(&Asm[(16 * w + lr) * STR + 32 * k0 + 8 * lg]);
#pragma unroll
    for (int ti = 0; ti < 16; ++ti) {
      bf16x8 b = *(const bf16x8*)(Wdt + (size_t)(16 * ti + lr) * 256 + 32 * k0 + 8 * lg);
      acc[ti] = __builtin_amdgcn_mfma_f32_16x16x32_bf16(a, b, acc[ti], 0, 0, 0);
    }
  }
#pragma unroll
  for (int ti = 0; ti < 16; ++ti) {
    int n = 16 * ti + lr;
    float bias = bd[n];
#pragma unroll
    for (int r = 0; r < 4; ++r) {
      int m = m0 + 16 * w + 4 * lg + r;
      y[(size_t)m * DD + n] = acc[ti][r] + bias;
    }
  }
}

// Sequential GRU scan, one workgroup (8 waves). Wave w owns units [32w,32w+32).
// U k-steps 0..5 in registers, k-steps 6..7 (k in [192,256)) in LDS.
__launch_bounds__(512, 2)
__global__ void gru_scan_kernel(const unsigned short* __restrict__ xgp, // [B*T][256][4] bf16 (xz,xr,xh,pad)
                                const unsigned short* __restrict__ Ut,  // [768][256] bf16 (transposed)
                                const float* __restrict__ brec,         // [768] = b[1]
                                const float* __restrict__ h0,           // [256]
                                float* __restrict__ y,                  // [B][T][256] fp32
                                int resid) {
  __shared__ unsigned short Utail[GG * 72];   // rows=gate col, 72 u16 stride (144B), k 192..255
  __shared__ unsigned short Hsm[BB * STR];    // h bf16, row stride 560B
  __shared__ unsigned short XGsm[BB * 1024];  // [b][u][4] bf16 staged per step

  const int tid = threadIdx.x;
  const int w = tid >> 6;
  const int l = tid & 63;
  const int lr = l & 15;
  const int lg = l >> 4;

  // Stage U k-tail into LDS (768 rows x 64 bf16)
  for (int i = 0; i < 12; ++i) {
    int c = i * 512 + tid;
    int row = c >> 3, part = c & 7;
    u16x8 v = *(const u16x8*)(Ut + (size_t)row * 256 + 192 + part * 8);
    *(u16x8*)(&Utail[row * 72 + part * 8]) = v;
  }

  // Register-resident U fragments, k-steps 0..5, for this wave's (z,r,h) triples
  bf16x8 uf[2][3][6];
  float bias[2][3];
#pragma unroll
  for (int tri = 0; tri < 2; ++tri) {
    int u = 32 * w + 16 * tri + lr;
#pragma unroll
    for (int g = 0; g < 3; ++g) {
      int n = g * 256 + u;
      bias[tri][g] = brec[n];
#pragma unroll
      for (int k0 = 0; k0 < 6; ++k0)
        uf[tri][g][k0] = *(const bf16x8*)(Ut + (size_t)n * 256 + 32 * k0 + 8 * lg);
    }
  }

  // h init (broadcast h0 across batch)
  float hprev[2][4];
#pragma unroll
  for (int tri = 0; tri < 2; ++tri) {
    int u = 32 * w + 16 * tri + lr;
    float hv = h0[u];
#pragma unroll
    for (int r = 0; r < 4; ++r) {
      hprev[tri][r] = hv;
      int b = 4 * lg + r;
      Hsm[b * STR + u] = f2bf(hv);
    }
  }
  __syncthreads();

  for (int t = 0; t < TT; ++t) {
    // Async stage xg_t (wave w handles batches 2w, 2w+1)
#pragma unroll
    for (int bb2 = 0; bb2 < 2; ++bb2) {
      int b = 2 * w + bb2;
      const unsigned short* src = xgp + ((size_t)b * TT + t) * 1024;
#pragma unroll
      for (int half = 0; half < 2; ++half) {
        const unsigned short* g = src + half * 512 + l * 8;
        unsigned short* ld = &XGsm[b * 1024 + half * 512];
        __builtin_amdgcn_global_load_lds(
            (const __attribute__((address_space(1))) unsigned int*)g,
            (__attribute__((address_space(3))) unsigned int*)ld, 16, 0, 0);
      }
    }
    // Residual prefetch
    float ypref[2][4];
    if (resid) {
#pragma unroll
      for (int tri = 0; tri < 2; ++tri) {
        int u = 32 * w + 16 * tri + lr;
#pragma unroll
        for (int r = 0; r < 4; ++r) {
          int b = 4 * lg + r;
          ypref[tri][r] = y[((size_t)b * TT + t) * UU + u];
        }
      }
    }
    // rg = h @ U + b_rec (bias in acc init)
    f32x4 acc[2][3];
#pragma unroll
    for (int tri = 0; tri < 2; ++tri)
#pragma unroll
      for (int g = 0; g < 3; ++g) {
        float bv = bias[tri][g];
        acc[tri][g] = (f32x4){bv, bv, bv, bv};
      }
#pragma unroll
    for (int k0 = 0; k0 < 8; ++k0) {
      bf16x8 a = *(const bf16x8*)(&Hsm[lr * STR + 32 * k0 + 8 * lg]);
      if (k0 < 6) {
#pragma unroll
        for (int tri = 0; tri < 2; ++tri)
#pragma unroll
          for (int g = 0; g < 3; ++g)
            acc[tri][g] = __builtin_amdgcn_mfma_f32_16x16x32_bf16(a, uf[tri][g][k0], acc[tri][g], 0, 0, 0);
      } else {
#pragma unroll
        for (int tri = 0; tri < 2; ++tri)
#pragma unroll
          for (int g = 0; g < 3; ++g) {
            int n = g * 256 + 32 * w + 16 * tri + lr;
            bf16x8 bfr = *(const bf16x8*)(&Utail[n * 72 + (k0 - 6) * 32 + 8 * lg]);
            acc[tri][g] = __builtin_amdgcn_mfma_f32_16x16x32_bf16(a, bfr, acc[tri][g], 0, 0, 0);
          }
      }
    }
    __syncthreads();  // Hsm reads done; XGsm staged (barrier drains vmcnt)

    // Gate math fully in registers; lane owns (b = 4*lg+r, u = 32w+16tri+lr)
#pragma unroll
    for (int tri = 0; tri < 2; ++tri) {
      int u = 32 * w + 16 * tri + lr;
#pragma unroll
      for (int r = 0; r < 4; ++r) {
        int b = 4 * lg + r;
        u16x4 xv = *(const u16x4*)(&XGsm[b * 1024 + u * 4]);
        float xz = bf2f(xv.x), xr = bf2f(xv.y), xh = bf2f(xv.z);
        float h = hprev[tri][r];
        float z = sigm(xz + acc[tri][0][r]);
        float rg = sigm(xr + acc[tri][1][r]);
        float hh = tanh_(xh + rg * acc[tri][2][r]);
        float cand = hh + z * (h - hh);
        float hnew = cand + ZONEOUT * (h - cand);
        hprev[tri][r] = hnew;
        Hsm[b * STR + u] = f2bf(hnew);
        float ov = cand;
        if (resid) ov += ypref[tri][r];
        y[((size_t)b * TT + t) * UU + u] = ov;
      }
    }
    __syncthreads();  // Hsm ready for next step's MFMA
  }
}

extern "C" void kernel_launch(void* const* d_in, const int* in_sizes, int n_in,
                              void* d_out, int out_size, void* d_ws, size_t ws_size,
                              hipStream_t stream) {
  const float* x = (const float*)d_in[0];
  const float* W[3]  = {(const float*)d_in[1], (const float*)d_in[5], (const float*)d_in[9]};
  const float* Um[3] = {(const float*)d_in[2], (const float*)d_in[6], (const float*)d_in[10]};
  const float* bm[3] = {(const float*)d_in[3], (const float*)d_in[7], (const float*)d_in[11]};
  const float* h0m[3] = {(const float*)d_in[4], (const float*)d_in[8], (const float*)d_in[12]};
  const float* Wd = (const float*)d_in[13];
  const float* bd = (const float*)d_in[14];
  float* out = (float*)d_out;

  char* ws = (char*)d_ws;
  unsigned short* xgp = (unsigned short*)ws;  // [65536][256][4] bf16 = 134,217,728 B
  size_t off = (size_t)65536 * 1024 * 2;
  unsigned short* Ut[3];
  unsigned short* Wt[3];
  for (int l = 0; l < 3; ++l) { Ut[l] = (unsigned short*)(ws + off); off += (size_t)768 * 256 * 2; }
  for (int l = 0; l < 3; ++l) { Wt[l] = (unsigned short*)(ws + off); off += (size_t)768 * 256 * 2; }
  unsigned short* Wdt = (unsigned short*)(ws + off); off += (size_t)256 * 256 * 2;

  const int tgrid = (768 * 256 + 255) / 256;
  for (int l = 0; l < 3; ++l) {
    hipLaunchKernelGGL(transpose_cast_kernel, dim3(tgrid), dim3(256), 0, stream, Um[l], Ut[l], 256, 768);
    hipLaunchKernelGGL(transpose_cast_kernel, dim3(tgrid), dim3(256), 0, stream, W[l], Wt[l], 256, 768);
  }
  hipLaunchKernelGGL(transpose_cast_kernel, dim3((256 * 256 + 255) / 256), dim3(256), 0, stream,
                     Wd, Wdt, 256, 256);

  for (int l = 0; l < 3; ++l) {
    const float* in_l = (l == 0) ? x : out;
    hipLaunchKernelGGL(gates_gemm_kernel, dim3(1024, 12), dim3(256), 0, stream,
                       in_l, Wt[l], bm[l], xgp);
    hipLaunchKernelGGL(gru_scan_kernel, dim3(1), dim3(512), 0, stream,
                       xgp, Ut[l], bm[l] + 768, h0m[l], out, l ? 1 : 0);
  }
  hipLaunchKernelGGL(head_gemm_kernel, dim3(1024), dim3(256), 0, stream, out, Wdt, bd);
}

// Round 3
// 35734.698 us; speedup vs baseline: 1.1666x; 1.1666x over previous
//
#include <hip/hip_runtime.h>
#include <cstdint>
#include <cstddef>

#define ZONEOUT 0.1f

typedef __attribute__((ext_vector_type(8))) short bf16x8;
typedef __attribute__((ext_vector_type(4))) float f32x4;
typedef __attribute__((ext_vector_type(4))) unsigned short u16x4;
typedef __attribute__((ext_vector_type(8))) unsigned short u16x8;
typedef __attribute__((ext_vector_type(4))) float float4_;

static constexpr int BB = 16;    // batch
static constexpr int TT = 4096;  // time
static constexpr int DD = 256;   // model dim
static constexpr int UU = 256;   // units
static constexpr int GG = 768;   // 3*UU
static constexpr int STR = 280;  // u16 row stride for 256-col LDS tiles (140 dw -> 2-way banks, free)

__device__ __forceinline__ unsigned short f2bf(float f) {
  unsigned int u = __builtin_bit_cast(unsigned int, f);
  u = u + 0x7fffu + ((u >> 16) & 1u);
  return (unsigned short)(u >> 16);
}
__device__ __forceinline__ float bf2f(unsigned short s) {
  unsigned int u = ((unsigned int)s) << 16;
  return __builtin_bit_cast(float, u);
}
__device__ __forceinline__ float sigm(float x) {
  float e = __builtin_amdgcn_exp2f(-1.4426950408889634f * x);
  return __builtin_amdgcn_rcpf(1.0f + e);
}
__device__ __forceinline__ float tanh_(float x) {
  float e = __builtin_amdgcn_exp2f(2.8853900817779268f * x);
  return 1.0f - 2.0f * __builtin_amdgcn_rcpf(1.0f + e);
}

// dst[n*K + k] = (bf16) src[k*N + n]   (src: [K][N] fp32, dst: [N][K] bf16)
__global__ void transpose_cast_kernel(const float* __restrict__ src,
                                      unsigned short* __restrict__ dst,
                                      int K, int N) {
  int idx = blockIdx.x * blockDim.x + threadIdx.x;
  int total = K * N;
  if (idx < total) {
    int k = idx / N, n = idx - k * N;          // read-coalesced
    dst[(size_t)n * K + k] = f2bf(src[idx]);
  }
}

// xg[m][u][slot] = (In @ W)[m][g] + b_in[g];  g = slot*256 + u.  64x64 tile.
__launch_bounds__(256, 2)
__global__ void gates_gemm_kernel(const float* __restrict__ In,          // [M][256] fp32
                                  const unsigned short* __restrict__ Wt, // [768][256] bf16 (transposed)
                                  const float* __restrict__ bin,         // [768]
                                  unsigned short* __restrict__ xgp) {    // [M][256][4] bf16
  __shared__ unsigned short Asm[64 * STR];
  __shared__ unsigned short Bsm[64 * STR];
  const int m0 = blockIdx.x * 64;
  const int n0 = blockIdx.y * 64;
  const int tid = threadIdx.x;
  {
    int row = tid >> 2, cb = (tid & 3) * 64;
    const float* src = In + (size_t)(m0 + row) * DD + cb;
#pragma unroll
    for (int i = 0; i < 16; ++i) {
      float4_ v = *(const float4_*)(src + i * 4);
      u16x4 o;
      o.x = f2bf(v.x); o.y = f2bf(v.y); o.z = f2bf(v.z); o.w = f2bf(v.w);
      *(u16x4*)(&Asm[row * STR + cb + i * 4]) = o;
    }
  }
  {
#pragma unroll
    for (int i = 0; i < 8; ++i) {
      int c = i * 256 + tid;
      int row = c >> 5, part = c & 31;
      u16x8 v = *(const u16x8*)(Wt + (size_t)(n0 + row) * 256 + part * 8);
      *(u16x8*)(&Bsm[row * STR + part * 8]) = v;
    }
  }
  __syncthreads();
  const int w = tid >> 6, l = tid & 63, lr = l & 15, lg = l >> 4;
  f32x4 acc[4] = {};
#pragma unroll
  for (int k0 = 0; k0 < 8; ++k0) {
    bf16x8 a = *(const bf16x8*)(&Asm[(16 * w + lr) * STR + 32 * k0 + 8 * lg]);
#pragma unroll
    for (int ti = 0; ti < 4; ++ti) {
      bf16x8 b = *(const bf16x8*)(&Bsm[(16 * ti + lr) * STR + 32 * k0 + 8 * lg]);
      acc[ti] = __builtin_amdgcn_mfma_f32_16x16x32_bf16(a, b, acc[ti], 0, 0, 0);
    }
  }
#pragma unroll
  for (int ti = 0; ti < 4; ++ti) {
    int gcol = n0 + 16 * ti + lr;
    float bias = bin[gcol];
    int u = gcol & 255, slot = gcol >> 8;
#pragma unroll
    for (int r = 0; r < 4; ++r) {
      int m = m0 + 16 * w + 4 * lg + r;
      xgp[(size_t)m * 1024 + u * 4 + slot] = f2bf(acc[ti][r] + bias);
    }
  }
}

// In-place dense head: y[m][:] = (bf16)y[m][:] @ Wd + bd.  64-row blocks, BN=256.
__launch_bounds__(256, 2)
__global__ void head_gemm_kernel(float* __restrict__ y,                   // [M][256] fp32, in-place
                                 const unsigned short* __restrict__ Wdt,  // [256][256] bf16 (transposed)
                                 const float* __restrict__ bd) {          // [256]
  __shared__ unsigned short Asm[64 * STR];
  const int m0 = blockIdx.x * 64;
  const int tid = threadIdx.x;
  {
    int row = tid >> 2, cb = (tid & 3) * 64;
    const float* src = y + (size_t)(m0 + row) * UU + cb;
#pragma unroll
    for (int i = 0; i < 16; ++i) {
      float4_ v = *(const float4_*)(src + i * 4);
      u16x4 o;
      o.x = f2bf(v.x); o.y = f2bf(v.y); o.z = f2bf(v.z); o.w = f2bf(v.w);
      *(u16x4*)(&Asm[row * STR + cb + i * 4]) = o;
    }
  }
  __syncthreads();
  const int w = tid >> 6, l = tid & 63, lr = l & 15, lg = l >> 4;
  f32x4 acc[16] = {};
#pragma unroll
  for (int k0 = 0; k0 < 8; ++k0) {
    bf16x8 a = *(const bf16x8*)(&Asm[(16 * w + lr) * STR + 32 * k0 + 8 * lg]);
#pragma unroll
    for (int ti = 0; ti < 16; ++ti) {
      bf16x8 b = *(const bf16x8*)(Wdt + (size_t)(16 * ti + lr) * 256 + 32 * k0 + 8 * lg);
      acc[ti] = __builtin_amdgcn_mfma_f32_16x16x32_bf16(a, b, acc[ti], 0, 0, 0);
    }
  }
#pragma unroll
  for (int ti = 0; ti < 16; ++ti) {
    int n = 16 * ti + lr;
    float bias = bd[n];
#pragma unroll
    for (int r = 0; r < 4; ++r) {
      int m = m0 + 16 * w + 4 * lg + r;
      y[(size_t)m * DD + n] = acc[ti][r] + bias;
    }
  }
}

// Sequential GRU scan, one workgroup (8 waves). Wave w owns units [32w,32w+32).
// U k-steps 0..5 in registers (forced 256-VGPR budget), k-steps 6..7 in LDS.
// xg loaded per-lane (no LDS staging); y stores deferred one step so their
// ack latency drains under the next step's MFMA window.
__global__ void __attribute__((amdgpu_flat_work_group_size(512, 512), amdgpu_waves_per_eu(2, 2)))
gru_scan_kernel(const unsigned short* __restrict__ xgp, // [B*T][256][4] bf16 (xz,xr,xh,pad)
                const unsigned short* __restrict__ Ut,  // [768][256] bf16 (transposed)
                const float* __restrict__ brec,         // [768] = b[1]
                const float* __restrict__ h0,           // [256]
                float* __restrict__ y,                  // [B][T][256] fp32
                int resid) {
  __shared__ unsigned short Utail[GG * 72];   // rows=gate col, 72 u16 stride (144B), k 192..255
  __shared__ unsigned short Hsm[BB * STR];    // h bf16

  const int tid = threadIdx.x;
  const int w = tid >> 6;
  const int l = tid & 63;
  const int lr = l & 15;
  const int lg = l >> 4;

  // Stage U k-tail into LDS (768 rows x 64 bf16)
  for (int i = 0; i < 12; ++i) {
    int c = i * 512 + tid;
    int row = c >> 3, part = c & 7;
    u16x8 v = *(const u16x8*)(Ut + (size_t)row * 256 + 192 + part * 8);
    *(u16x8*)(&Utail[row * 72 + part * 8]) = v;
  }

  // Register-resident U fragments, k-steps 0..5, for this wave's (z,r,h) triples
  bf16x8 uf[2][3][6];
  float bias[2][3];
#pragma unroll
  for (int tri = 0; tri < 2; ++tri) {
    int u = 32 * w + 16 * tri + lr;
#pragma unroll
    for (int g = 0; g < 3; ++g) {
      int n = g * 256 + u;
      bias[tri][g] = brec[n];
#pragma unroll
      for (int k0 = 0; k0 < 6; ++k0)
        uf[tri][g][k0] = *(const bf16x8*)(Ut + (size_t)n * 256 + 32 * k0 + 8 * lg);
    }
  }

  // h init (broadcast h0 across batch)
  float hprev[2][4];
#pragma unroll
  for (int tri = 0; tri < 2; ++tri) {
    int u = 32 * w + 16 * tri + lr;
    float hv = h0[u];
#pragma unroll
    for (int r = 0; r < 4; ++r) {
      hprev[tri][r] = hv;
      int b = 4 * lg + r;
      Hsm[b * STR + u] = f2bf(hv);
    }
  }
  __syncthreads();

  float ycand[2][4];  // deferred y values (step t-1)

  for (int t = 0; t < TT; ++t) {
    // Deferred stores of y(t-1): drain under this step's MFMA window
    if (t > 0) {
#pragma unroll
      for (int tri = 0; tri < 2; ++tri) {
        int u = 32 * w + 16 * tri + lr;
#pragma unroll
        for (int r = 0; r < 4; ++r) {
          int b = 4 * lg + r;
          y[((size_t)b * TT + (t - 1)) * UU + u] = ycand[tri][r];
        }
      }
    }
    // Direct per-lane xg(t) loads (16-lane groups read 128B contiguous)
    u16x4 xv[2][4];
#pragma unroll
    for (int tri = 0; tri < 2; ++tri) {
      int u = 32 * w + 16 * tri + lr;
#pragma unroll
      for (int r = 0; r < 4; ++r) {
        int b = 4 * lg + r;
        xv[tri][r] = *(const u16x4*)(xgp + ((size_t)b * TT + t) * 1024 + u * 4);
      }
    }
    // Residual prefetch
    float ypref[2][4];
    if (resid) {
#pragma unroll
      for (int tri = 0; tri < 2; ++tri) {
        int u = 32 * w + 16 * tri + lr;
#pragma unroll
        for (int r = 0; r < 4; ++r) {
          int b = 4 * lg + r;
          ypref[tri][r] = y[((size_t)b * TT + t) * UU + u];
        }
      }
    }
    // rg = h @ U + b_rec (bias in acc init)
    f32x4 acc[2][3];
#pragma unroll
    for (int tri = 0; tri < 2; ++tri)
#pragma unroll
      for (int g = 0; g < 3; ++g) {
        float bv = bias[tri][g];
        acc[tri][g] = (f32x4){bv, bv, bv, bv};
      }
#pragma unroll
    for (int k0 = 0; k0 < 8; ++k0) {
      bf16x8 a = *(const bf16x8*)(&Hsm[lr * STR + 32 * k0 + 8 * lg]);
      if (k0 < 6) {
#pragma unroll
        for (int tri = 0; tri < 2; ++tri)
#pragma unroll
          for (int g = 0; g < 3; ++g)
            acc[tri][g] = __builtin_amdgcn_mfma_f32_16x16x32_bf16(a, uf[tri][g][k0], acc[tri][g], 0, 0, 0);
      } else {
#pragma unroll
        for (int tri = 0; tri < 2; ++tri)
#pragma unroll
          for (int g = 0; g < 3; ++g) {
            int n = g * 256 + 32 * w + 16 * tri + lr;
            bf16x8 bfr = *(const bf16x8*)(&Utail[n * 72 + (k0 - 6) * 32 + 8 * lg]);
            acc[tri][g] = __builtin_amdgcn_mfma_f32_16x16x32_bf16(a, bfr, acc[tri][g], 0, 0, 0);
          }
      }
    }
    __syncthreads();  // Hsm reads done; all vmem (stores(t-1), xv, ypref) drained here

    // Gate math fully in registers; lane owns (b = 4*lg+r, u = 32w+16tri+lr)
#pragma unroll
    for (int tri = 0; tri < 2; ++tri) {
      int u = 32 * w + 16 * tri + lr;
#pragma unroll
      for (int r = 0; r < 4; ++r) {
        int b = 4 * lg + r;
        u16x4 xvv = xv[tri][r];
        float xz = bf2f(xvv.x), xr = bf2f(xvv.y), xh = bf2f(xvv.z);
        float h = hprev[tri][r];
        float z = sigm(xz + acc[tri][0][r]);
        float rg = sigm(xr + acc[tri][1][r]);
        float hh = tanh_(xh + rg * acc[tri][2][r]);
        float cand = hh + z * (h - hh);
        float hnew = cand + ZONEOUT * (h - cand);
        hprev[tri][r] = hnew;
        Hsm[b * STR + u] = f2bf(hnew);
        float ov = cand;
        if (resid) ov += ypref[tri][r];
        ycand[tri][r] = ov;  // store deferred to next step
      }
    }
    __syncthreads();  // Hsm ready for next step's MFMA (no vmem issued in gate phase)
  }
  // Flush final step's y
#pragma unroll
  for (int tri = 0; tri < 2; ++tri) {
    int u = 32 * w + 16 * tri + lr;
#pragma unroll
    for (int r = 0; r < 4; ++r) {
      int b = 4 * lg + r;
      y[((size_t)b * TT + (TT - 1)) * UU + u] = ycand[tri][r];
    }
  }
}

extern "C" void kernel_launch(void* const* d_in, const int* in_sizes, int n_in,
                              void* d_out, int out_size, void* d_ws, size_t ws_size,
                              hipStream_t stream) {
  const float* x = (const float*)d_in[0];
  const float* W[3]  = {(const float*)d_in[1], (const float*)d_in[5], (const float*)d_in[9]};
  const float* Um[3] = {(const float*)d_in[2], (const float*)d_in[6], (const float*)d_in[10]};
  const float* bm[3] = {(const float*)d_in[3], (const float*)d_in[7], (const float*)d_in[11]};
  const float* h0m[3] = {(const float*)d_in[4], (const float*)d_in[8], (const float*)d_in[12]};
  const float* Wd = (const float*)d_in[13];
  const float* bd = (const float*)d_in[14];
  float* out = (float*)d_out;

  char* ws = (char*)d_ws;
  unsigned short* xgp = (unsigned short*)ws;  // [65536][256][4] bf16 = 134,217,728 B
  size_t off = (size_t)65536 * 1024 * 2;
  unsigned short* Ut[3];
  unsigned short* Wt[3];
  for (int l = 0; l < 3; ++l) { Ut[l] = (unsigned short*)(ws + off); off += (size_t)768 * 256 * 2; }
  for (int l = 0; l < 3; ++l) { Wt[l] = (unsigned short*)(ws + off); off += (size_t)768 * 256 * 2; }
  unsigned short* Wdt = (unsigned short*)(ws + off); off += (size_t)256 * 256 * 2;

  const int tgrid = (768 * 256 + 255) / 256;
  for (int l = 0; l < 3; ++l) {
    hipLaunchKernelGGL(transpose_cast_kernel, dim3(tgrid), dim3(256), 0, stream, Um[l], Ut[l], 256, 768);
    hipLaunchKernelGGL(transpose_cast_kernel, dim3(tgrid), dim3(256), 0, stream, W[l], Wt[l], 256, 768);
  }
  hipLaunchKernelGGL(transpose_cast_kernel, dim3((256 * 256 + 255) / 256), dim3(256), 0, stream,
                     Wd, Wdt, 256, 256);

  for (int l = 0; l < 3; ++l) {
    const float* in_l = (l == 0) ? x : out;
    hipLaunchKernelGGL(gates_gemm_kernel, dim3(1024, 12), dim3(256), 0, stream,
                       in_l, Wt[l], bm[l], xgp);
    hipLaunchKernelGGL(gru_scan_kernel, dim3(1), dim3(512), 0, stream,
                       xgp, Ut[l], bm[l] + 768, h0m[l], out, l ? 1 : 0);
  }
  hipLaunchKernelGGL(head_gemm_kernel, dim3(1024), dim3(256), 0, stream, out, Wdt, bd);
}

// Round 4
// 28222.574 us; speedup vs baseline: 1.4771x; 1.2662x over previous
//
#include <hip/hip_runtime.h>
#include <cstdint>
#include <cstddef>

#define ZONEOUT 0.1f

typedef __attribute__((ext_vector_type(8))) short bf16x8;
typedef __attribute__((ext_vector_type(4))) float f32x4;
typedef __attribute__((ext_vector_type(4))) unsigned short u16x4;
typedef __attribute__((ext_vector_type(8))) unsigned short u16x8;
typedef __attribute__((ext_vector_type(4))) float float4_;

static constexpr int BB = 16;    // batch
static constexpr int TT = 4096;  // time
static constexpr int DD = 256;   // model dim
static constexpr int UU = 256;   // units
static constexpr int GG = 768;   // 3*UU
static constexpr int STR = 280;  // u16 row stride for 256-col LDS tiles (140 dw -> 2-way banks, free)

__device__ __forceinline__ unsigned short f2bf(float f) {
  unsigned int u = __builtin_bit_cast(unsigned int, f);
  u = u + 0x7fffu + ((u >> 16) & 1u);
  return (unsigned short)(u >> 16);
}
__device__ __forceinline__ float bf2f(unsigned short s) {
  unsigned int u = ((unsigned int)s) << 16;
  return __builtin_bit_cast(float, u);
}
__device__ __forceinline__ float sigm(float x) {
  float e = __builtin_amdgcn_exp2f(-1.4426950408889634f * x);
  return __builtin_amdgcn_rcpf(1.0f + e);
}
__device__ __forceinline__ float tanh_(float x) {
  float e = __builtin_amdgcn_exp2f(2.8853900817779268f * x);
  return 1.0f - 2.0f * __builtin_amdgcn_rcpf(1.0f + e);
}

// Workgroup barrier WITHOUT vmcnt(0) drain: LDS-visibility only.
// Safe here: all cross-wave hazards in the scan are LDS; global y/xg are
// partitioned by unit-range per wave identically for loads and stores.
__device__ __forceinline__ void wg_barrier_lds() {
  asm volatile("s_waitcnt lgkmcnt(0)\n\ts_barrier" ::: "memory");
}

// dst[n*K + k] = (bf16) src[k*N + n]   (src: [K][N] fp32, dst: [N][K] bf16)
__global__ void transpose_cast_kernel(const float* __restrict__ src,
                                      unsigned short* __restrict__ dst,
                                      int K, int N) {
  int idx = blockIdx.x * blockDim.x + threadIdx.x;
  int total = K * N;
  if (idx < total) {
    int k = idx / N, n = idx - k * N;          // read-coalesced
    dst[(size_t)n * K + k] = f2bf(src[idx]);
  }
}

// xg[m][u][slot] = (In @ W)[m][g] + b_in[g];  g = slot*256 + u.  64x64 tile.
__launch_bounds__(256, 2)
__global__ void gates_gemm_kernel(const float* __restrict__ In,          // [M][256] fp32
                                  const unsigned short* __restrict__ Wt, // [768][256] bf16 (transposed)
                                  const float* __restrict__ bin,         // [768]
                                  unsigned short* __restrict__ xgp) {    // [M][256][4] bf16
  __shared__ unsigned short Asm[64 * STR];
  __shared__ unsigned short Bsm[64 * STR];
  const int m0 = blockIdx.x * 64;
  const int n0 = blockIdx.y * 64;
  const int tid = threadIdx.x;
  {
    int row = tid >> 2, cb = (tid & 3) * 64;
    const float* src = In + (size_t)(m0 + row) * DD + cb;
#pragma unroll
    for (int i = 0; i < 16; ++i) {
      float4_ v = *(const float4_*)(src + i * 4);
      u16x4 o;
      o.x = f2bf(v.x); o.y = f2bf(v.y); o.z = f2bf(v.z); o.w = f2bf(v.w);
      *(u16x4*)(&Asm[row * STR + cb + i * 4]) = o;
    }
  }
  {
#pragma unroll
    for (int i = 0; i < 8; ++i) {
      int c = i * 256 + tid;
      int row = c >> 5, part = c & 31;
      u16x8 v = *(const u16x8*)(Wt + (size_t)(n0 + row) * 256 + part * 8);
      *(u16x8*)(&Bsm[row * STR + part * 8]) = v;
    }
  }
  __syncthreads();
  const int w = tid >> 6, l = tid & 63, lr = l & 15, lg = l >> 4;
  f32x4 acc[4] = {};
#pragma unroll
  for (int k0 = 0; k0 < 8; ++k0) {
    bf16x8 a = *(const bf16x8*)(&Asm[(16 * w + lr) * STR + 32 * k0 + 8 * lg]);
#pragma unroll
    for (int ti = 0; ti < 4; ++ti) {
      bf16x8 b = *(const bf16x8*)(&Bsm[(16 * ti + lr) * STR + 32 * k0 + 8 * lg]);
      acc[ti] = __builtin_amdgcn_mfma_f32_16x16x32_bf16(a, b, acc[ti], 0, 0, 0);
    }
  }
#pragma unroll
  for (int ti = 0; ti < 4; ++ti) {
    int gcol = n0 + 16 * ti + lr;
    float bias = bin[gcol];
    int u = gcol & 255, slot = gcol >> 8;
#pragma unroll
    for (int r = 0; r < 4; ++r) {
      int m = m0 + 16 * w + 4 * lg + r;
      xgp[(size_t)m * 1024 + u * 4 + slot] = f2bf(acc[ti][r] + bias);
    }
  }
}

// In-place dense head: y[m][:] = (bf16)y[m][:] @ Wd + bd.  64-row blocks, BN=256.
__launch_bounds__(256, 2)
__global__ void head_gemm_kernel(float* __restrict__ y,                   // [M][256] fp32, in-place
                                 const unsigned short* __restrict__ Wdt,  // [256][256] bf16 (transposed)
                                 const float* __restrict__ bd) {          // [256]
  __shared__ unsigned short Asm[64 * STR];
  const int m0 = blockIdx.x * 64;
  const int tid = threadIdx.x;
  {
    int row = tid >> 2, cb = (tid & 3) * 64;
    const float* src = y + (size_t)(m0 + row) * UU + cb;
#pragma unroll
    for (int i = 0; i < 16; ++i) {
      float4_ v = *(const float4_*)(src + i * 4);
      u16x4 o;
      o.x = f2bf(v.x); o.y = f2bf(v.y); o.z = f2bf(v.z); o.w = f2bf(v.w);
      *(u16x4*)(&Asm[row * STR + cb + i * 4]) = o;
    }
  }
  __syncthreads();
  const int w = tid >> 6, l = tid & 63, lr = l & 15, lg = l >> 4;
  f32x4 acc[16] = {};
#pragma unroll
  for (int k0 = 0; k0 < 8; ++k0) {
    bf16x8 a = *(const bf16x8*)(&Asm[(16 * w + lr) * STR + 32 * k0 + 8 * lg]);
#pragma unroll
    for (int ti = 0; ti < 16; ++ti) {
      bf16x8 b = *(const bf16x8*)(Wdt + (size_t)(16 * ti + lr) * 256 + 32 * k0 + 8 * lg);
      acc[ti] = __builtin_amdgcn_mfma_f32_16x16x32_bf16(a, b, acc[ti], 0, 0, 0);
    }
  }
#pragma unroll
  for (int ti = 0; ti < 16; ++ti) {
    int n = 16 * ti + lr;
    float bias = bd[n];
#pragma unroll
    for (int r = 0; r < 4; ++r) {
      int m = m0 + 16 * w + 4 * lg + r;
      y[(size_t)m * DD + n] = acc[ti][r] + bias;
    }
  }
}

// Sequential GRU scan, one workgroup (8 waves). Wave w owns units [32w,32w+32).
// U k-steps 0..5 pinned in registers via opaque asm, k-steps 6..7 in LDS.
// Double-buffered Hsm -> single LDS-only barrier per step; xg prefetched one
// step ahead into the just-freed xv registers.
__global__ void __attribute__((amdgpu_flat_work_group_size(512, 512), amdgpu_waves_per_eu(2, 2)))
gru_scan_kernel(const unsigned short* __restrict__ xgp, // [B*T][256][4] bf16 (xz,xr,xh,pad)
                const unsigned short* __restrict__ Ut,  // [768][256] bf16 (transposed)
                const float* __restrict__ brec,         // [768] = b[1]
                const float* __restrict__ h0,           // [256]
                float* __restrict__ y,                  // [B][T][256] fp32
                int resid) {
  __shared__ unsigned short Utail[GG * 72];      // k 192..255, row stride 144B
  __shared__ unsigned short Hsm[2][BB * STR];    // double-buffered h (bf16)

  const int tid = threadIdx.x;
  const int w = tid >> 6;
  const int l = tid & 63;
  const int lr = l & 15;
  const int lg = l >> 4;

  // Stage U k-tail into LDS (768 rows x 64 bf16)
  for (int i = 0; i < 12; ++i) {
    int c = i * 512 + tid;
    int row = c >> 3, part = c & 7;
    u16x8 v = *(const u16x8*)(Ut + (size_t)row * 256 + 192 + part * 8);
    *(u16x8*)(&Utail[row * 72 + part * 8]) = v;
  }

  // Register-resident U fragments (k-steps 0..5) for this wave's (z,r,h) triples.
  // Loaded as f32x4 views; pinned below so the compiler cannot re-sink the loads.
  f32x4 ufr[2][3][6];
  float bias[2][3];
#pragma unroll
  for (int tri = 0; tri < 2; ++tri) {
    int u = 32 * w + 16 * tri + lr;
#pragma unroll
    for (int g = 0; g < 3; ++g) {
      int n = g * 256 + u;
      bias[tri][g] = brec[n];
#pragma unroll
      for (int k0 = 0; k0 < 6; ++k0)
        ufr[tri][g][k0] = *(const f32x4*)(Ut + (size_t)n * 256 + 32 * k0 + 8 * lg);
    }
  }
  // Opaque pin: forces all 36 fragments (144 VGPRs) to stay register-resident.
#pragma unroll
  for (int tri = 0; tri < 2; ++tri)
#pragma unroll
    for (int g = 0; g < 3; ++g)
#pragma unroll
      for (int k0 = 0; k0 < 6; ++k0)
        asm volatile("" : "+v"(ufr[tri][g][k0]));

  // h init (broadcast h0 across batch) into buffer 0
  float hprev[2][4];
#pragma unroll
  for (int tri = 0; tri < 2; ++tri) {
    int u = 32 * w + 16 * tri + lr;
    float hv = h0[u];
#pragma unroll
    for (int r = 0; r < 4; ++r) {
      hprev[tri][r] = hv;
      int b = 4 * lg + r;
      Hsm[0][b * STR + u] = f2bf(hv);
    }
  }

  // Prefetch xg(0)
  u16x4 xv[2][4];
#pragma unroll
  for (int tri = 0; tri < 2; ++tri) {
    int u = 32 * w + 16 * tri + lr;
#pragma unroll
    for (int r = 0; r < 4; ++r) {
      int b = 4 * lg + r;
      xv[tri][r] = *(const u16x4*)(xgp + ((size_t)b * TT) * 1024 + u * 4);
    }
  }
  wg_barrier_lds();

  for (int t = 0; t < TT; ++t) {
    const unsigned short* cur = &Hsm[t & 1][0];
    unsigned short* nxt = &Hsm[(t + 1) & 1][0];

    // Residual prefetch (window = MFMA phase)
    float ypref[2][4];
    if (resid) {
#pragma unroll
      for (int tri = 0; tri < 2; ++tri) {
        int u = 32 * w + 16 * tri + lr;
#pragma unroll
        for (int r = 0; r < 4; ++r) {
          int b = 4 * lg + r;
          ypref[tri][r] = y[((size_t)b * TT + t) * UU + u];
        }
      }
    }

    // rg = h @ U + b_rec (bias in acc init)
    f32x4 acc[2][3];
#pragma unroll
    for (int tri = 0; tri < 2; ++tri)
#pragma unroll
      for (int g = 0; g < 3; ++g) {
        float bv = bias[tri][g];
        acc[tri][g] = (f32x4){bv, bv, bv, bv};
      }
#pragma unroll
    for (int k0 = 0; k0 < 8; ++k0) {
      bf16x8 a = *(const bf16x8*)(&cur[lr * STR + 32 * k0 + 8 * lg]);
      if (k0 < 6) {
#pragma unroll
        for (int tri = 0; tri < 2; ++tri)
#pragma unroll
          for (int g = 0; g < 3; ++g)
            acc[tri][g] = __builtin_amdgcn_mfma_f32_16x16x32_bf16(
                a, __builtin_bit_cast(bf16x8, ufr[tri][g][k0]), acc[tri][g], 0, 0, 0);
      } else {
#pragma unroll
        for (int tri = 0; tri < 2; ++tri)
#pragma unroll
          for (int g = 0; g < 3; ++g) {
            int n = g * 256 + 32 * w + 16 * tri + lr;
            bf16x8 bfr = *(const bf16x8*)(&Utail[n * 72 + (k0 - 6) * 32 + 8 * lg]);
            acc[tri][g] = __builtin_amdgcn_mfma_f32_16x16x32_bf16(a, bfr, acc[tri][g], 0, 0, 0);
          }
      }
    }
    // NO barrier here: gate phase writes `nxt`, MFMA read `cur` (disjoint buffers).

    const int tn = (t + 1 < TT) ? t + 1 : t;  // prefetch target (capped; last discarded)
    // Gate math in registers; lane owns (b = 4*lg+r, u = 32w+16tri+lr)
#pragma unroll
    for (int tri = 0; tri < 2; ++tri) {
      int u = 32 * w + 16 * tri + lr;
#pragma unroll
      for (int r = 0; r < 4; ++r) {
        int b = 4 * lg + r;
        u16x4 xvv = xv[tri][r];
        // reload just-freed xv regs with xg(t+1): latency hides under barrier+next MFMA
        xv[tri][r] = *(const u16x4*)(xgp + ((size_t)b * TT + tn) * 1024 + u * 4);
        float xz = bf2f(xvv.x), xr = bf2f(xvv.y), xh = bf2f(xvv.z);
        float h = hprev[tri][r];
        float z = sigm(xz + acc[tri][0][r]);
        float rg = sigm(xr + acc[tri][1][r]);
        float hh = tanh_(xh + rg * acc[tri][2][r]);
        float cand = hh + z * (h - hh);
        float hnew = cand + ZONEOUT * (h - cand);
        hprev[tri][r] = hnew;
        nxt[b * STR + u] = f2bf(hnew);
        float ov = cand;
        if (resid) ov += ypref[tri][r];
        y[((size_t)b * TT + t) * UU + u] = ov;  // store never blocks (no vmcnt drain)
      }
    }
    wg_barrier_lds();  // nxt visible to all waves; vmem stays in flight
  }
}

extern "C" void kernel_launch(void* const* d_in, const int* in_sizes, int n_in,
                              void* d_out, int out_size, void* d_ws, size_t ws_size,
                              hipStream_t stream) {
  const float* x = (const float*)d_in[0];
  const float* W[3]  = {(const float*)d_in[1], (const float*)d_in[5], (const float*)d_in[9]};
  const float* Um[3] = {(const float*)d_in[2], (const float*)d_in[6], (const float*)d_in[10]};
  const float* bm[3] = {(const float*)d_in[3], (const float*)d_in[7], (const float*)d_in[11]};
  const float* h0m[3] = {(const float*)d_in[4], (const float*)d_in[8], (const float*)d_in[12]};
  const float* Wd = (const float*)d_in[13];
  const float* bd = (const float*)d_in[14];
  float* out = (float*)d_out;

  char* ws = (char*)d_ws;
  unsigned short* xgp = (unsigned short*)ws;  // [65536][256][4] bf16 = 134,217,728 B
  size_t off = (size_t)65536 * 1024 * 2;
  unsigned short* Ut[3];
  unsigned short* Wt[3];
  for (int l = 0; l < 3; ++l) { Ut[l] = (unsigned short*)(ws + off); off += (size_t)768 * 256 * 2; }
  for (int l = 0; l < 3; ++l) { Wt[l] = (unsigned short*)(ws + off); off += (size_t)768 * 256 * 2; }
  unsigned short* Wdt = (unsigned short*)(ws + off); off += (size_t)256 * 256 * 2;

  const int tgrid = (768 * 256 + 255) / 256;
  for (int l = 0; l < 3; ++l) {
    hipLaunchKernelGGL(transpose_cast_kernel, dim3(tgrid), dim3(256), 0, stream, Um[l], Ut[l], 256, 768);
    hipLaunchKernelGGL(transpose_cast_kernel, dim3(tgrid), dim3(256), 0, stream, W[l], Wt[l], 256, 768);
  }
  hipLaunchKernelGGL(transpose_cast_kernel, dim3((256 * 256 + 255) / 256), dim3(256), 0, stream,
                     Wd, Wdt, 256, 256);

  for (int l = 0; l < 3; ++l) {
    const float* in_l = (l == 0) ? x : out;
    hipLaunchKernelGGL(gates_gemm_kernel, dim3(1024, 12), dim3(256), 0, stream,
                       in_l, Wt[l], bm[l], xgp);
    hipLaunchKernelGGL(gru_scan_kernel, dim3(1), dim3(512), 0, stream,
                       xgp, Ut[l], bm[l] + 768, h0m[l], out, l ? 1 : 0);
  }
  hipLaunchKernelGGL(head_gemm_kernel, dim3(1024), dim3(256), 0, stream, out, Wdt, bd);
}

// Round 5
// 28196.957 us; speedup vs baseline: 1.4784x; 1.0009x over previous
//
#include <hip/hip_runtime.h>
#include <cstdint>
#include <cstddef>

#define ZONEOUT 0.1f

typedef __attribute__((ext_vector_type(8))) short bf16x8;
typedef __attribute__((ext_vector_type(4))) float f32x4;
typedef __attribute__((ext_vector_type(4))) unsigned short u16x4;
typedef __attribute__((ext_vector_type(8))) unsigned short u16x8;
typedef __attribute__((ext_vector_type(4))) float float4_;

static constexpr int BB = 16;    // batch
static constexpr int TT = 4096;  // time
static constexpr int DD = 256;   // model dim
static constexpr int UU = 256;   // units
static constexpr int GG = 768;   // 3*UU
static constexpr int STR = 280;  // u16 row stride for 256-col LDS tiles (140 dw -> 2-way banks, free)

__device__ __forceinline__ unsigned short f2bf(float f) {
  unsigned int u = __builtin_bit_cast(unsigned int, f);
  u = u + 0x7fffu + ((u >> 16) & 1u);
  return (unsigned short)(u >> 16);
}
__device__ __forceinline__ float bf2f(unsigned short s) {
  unsigned int u = ((unsigned int)s) << 16;
  return __builtin_bit_cast(float, u);
}
__device__ __forceinline__ float sigm(float x) {
  float e = __builtin_amdgcn_exp2f(-1.4426950408889634f * x);
  return __builtin_amdgcn_rcpf(1.0f + e);
}
__device__ __forceinline__ float tanh_(float x) {
  float e = __builtin_amdgcn_exp2f(2.8853900817779268f * x);
  return 1.0f - 2.0f * __builtin_amdgcn_rcpf(1.0f + e);
}

// Workgroup barrier WITHOUT vmcnt(0) drain: LDS-visibility only.
// Safe here: all cross-wave hazards in the scan are LDS; global y/xg are
// partitioned by unit-range per wave identically for loads and stores.
__device__ __forceinline__ void wg_barrier_lds() {
  asm volatile("s_waitcnt lgkmcnt(0)\n\ts_barrier" ::: "memory");
}

// dst[n*K + k] = (bf16) src[k*N + n]   (src: [K][N] fp32, dst: [N][K] bf16)
__global__ void transpose_cast_kernel(const float* __restrict__ src,
                                      unsigned short* __restrict__ dst,
                                      int K, int N) {
  int idx = blockIdx.x * blockDim.x + threadIdx.x;
  int total = K * N;
  if (idx < total) {
    int k = idx / N, n = idx - k * N;          // read-coalesced
    dst[(size_t)n * K + k] = f2bf(src[idx]);
  }
}

// xg[m][u][slot] = (In @ W)[m][g] + b_in[g];  g = slot*256 + u.  64x64 tile.
__launch_bounds__(256, 2)
__global__ void gates_gemm_kernel(const float* __restrict__ In,          // [M][256] fp32
                                  const unsigned short* __restrict__ Wt, // [768][256] bf16 (transposed)
                                  const float* __restrict__ bin,         // [768]
                                  unsigned short* __restrict__ xgp) {    // [M][256][4] bf16
  __shared__ unsigned short Asm[64 * STR];
  __shared__ unsigned short Bsm[64 * STR];
  const int m0 = blockIdx.x * 64;
  const int n0 = blockIdx.y * 64;
  const int tid = threadIdx.x;
  {
    int row = tid >> 2, cb = (tid & 3) * 64;
    const float* src = In + (size_t)(m0 + row) * DD + cb;
#pragma unroll
    for (int i = 0; i < 16; ++i) {
      float4_ v = *(const float4_*)(src + i * 4);
      u16x4 o;
      o.x = f2bf(v.x); o.y = f2bf(v.y); o.z = f2bf(v.z); o.w = f2bf(v.w);
      *(u16x4*)(&Asm[row * STR + cb + i * 4]) = o;
    }
  }
  {
#pragma unroll
    for (int i = 0; i < 8; ++i) {
      int c = i * 256 + tid;
      int row = c >> 5, part = c & 31;
      u16x8 v = *(const u16x8*)(Wt + (size_t)(n0 + row) * 256 + part * 8);
      *(u16x8*)(&Bsm[row * STR + part * 8]) = v;
    }
  }
  __syncthreads();
  const int w = tid >> 6, l = tid & 63, lr = l & 15, lg = l >> 4;
  f32x4 acc[4] = {};
#pragma unroll
  for (int k0 = 0; k0 < 8; ++k0) {
    bf16x8 a = *(const bf16x8*)(&Asm[(16 * w + lr) * STR + 32 * k0 + 8 * lg]);
#pragma unroll
    for (int ti = 0; ti < 4; ++ti) {
      bf16x8 b = *(const bf16x8*)(&Bsm[(16 * ti + lr) * STR + 32 * k0 + 8 * lg]);
      acc[ti] = __builtin_amdgcn_mfma_f32_16x16x32_bf16(a, b, acc[ti], 0, 0, 0);
    }
  }
#pragma unroll
  for (int ti = 0; ti < 4; ++ti) {
    int gcol = n0 + 16 * ti + lr;
    float bias = bin[gcol];
    int u = gcol & 255, slot = gcol >> 8;
#pragma unroll
    for (int r = 0; r < 4; ++r) {
      int m = m0 + 16 * w + 4 * lg + r;
      xgp[(size_t)m * 1024 + u * 4 + slot] = f2bf(acc[ti][r] + bias);
    }
  }
}

// In-place dense head: y[m][:] = (bf16)y[m][:] @ Wd + bd.  64-row blocks, BN=256.
__launch_bounds__(256, 2)
__global__ void head_gemm_kernel(float* __restrict__ y,                   // [M][256] fp32, in-place
                                 const unsigned short* __restrict__ Wdt,  // [256][256] bf16 (transposed)
                                 const float* __restrict__ bd) {          // [256]
  __shared__ unsigned short Asm[64 * STR];
  const int m0 = blockIdx.x * 64;
  const int tid = threadIdx.x;
  {
    int row = tid >> 2, cb = (tid & 3) * 64;
    const float* src = y + (size_t)(m0 + row) * UU + cb;
#pragma unroll
    for (int i = 0; i < 16; ++i) {
      float4_ v = *(const float4_*)(src + i * 4);
      u16x4 o;
      o.x = f2bf(v.x); o.y = f2bf(v.y); o.z = f2bf(v.z); o.w = f2bf(v.w);
      *(u16x4*)(&Asm[row * STR + cb + i * 4]) = o;
    }
  }
  __syncthreads();
  const int w = tid >> 6, l = tid & 63, lr = l & 15, lg = l >> 4;
  f32x4 acc[16] = {};
#pragma unroll
  for (int k0 = 0; k0 < 8; ++k0) {
    bf16x8 a = *(const bf16x8*)(&Asm[(16 * w + lr) * STR + 32 * k0 + 8 * lg]);
#pragma unroll
    for (int ti = 0; ti < 16; ++ti) {
      bf16x8 b = *(const bf16x8*)(Wdt + (size_t)(16 * ti + lr) * 256 + 32 * k0 + 8 * lg);
      acc[ti] = __builtin_amdgcn_mfma_f32_16x16x32_bf16(a, b, acc[ti], 0, 0, 0);
    }
  }
#pragma unroll
  for (int ti = 0; ti < 16; ++ti) {
    int n = 16 * ti + lr;
    float bias = bd[n];
#pragma unroll
    for (int r = 0; r < 4; ++r) {
      int m = m0 + 16 * w + 4 * lg + r;
      y[(size_t)m * DD + n] = acc[ti][r] + bias;
    }
  }
}

// Sequential GRU scan, one workgroup (8 waves). Wave w owns units [32w,32w+32).
// U k-steps 0..5 pinned in registers, k-steps 6..7 in LDS.
// amdgpu_num_vgpr(256): LDS already caps at 1 WG/CU (2 waves/SIMD), so a
// 256-VGPR/wave budget is free; the default heuristic stops at 128 and
// spills the 144-VGPR ufr array -> ~290KB/step L2 reload (the round-4 stall).
__global__ void __attribute__((amdgpu_flat_work_group_size(512, 512), amdgpu_num_vgpr(256)))
gru_scan_kernel(const unsigned short* __restrict__ xgp, // [B*T][256][4] bf16 (xz,xr,xh,pad)
                const unsigned short* __restrict__ Ut,  // [768][256] bf16 (transposed)
                const float* __restrict__ brec,         // [768] = b[1]
                const float* __restrict__ h0,           // [256]
                float* __restrict__ y,                  // [B][T][256] fp32
                int resid) {
  __shared__ unsigned short Utail[GG * 72];      // k 192..255, row stride 144B
  __shared__ unsigned short Hsm[2][BB * STR];    // double-buffered h (bf16)

  const int tid = threadIdx.x;
  const int w = tid >> 6;
  const int l = tid & 63;
  const int lr = l & 15;
  const int lg = l >> 4;

  // Stage U k-tail into LDS (768 rows x 64 bf16)
  for (int i = 0; i < 12; ++i) {
    int c = i * 512 + tid;
    int row = c >> 3, part = c & 7;
    u16x8 v = *(const u16x8*)(Ut + (size_t)row * 256 + 192 + part * 8);
    *(u16x8*)(&Utail[row * 72 + part * 8]) = v;
  }

  // Register-resident U fragments (k-steps 0..5) for this wave's (z,r,h) triples.
  f32x4 ufr[2][3][6];
  float bias[2][3];
#pragma unroll
  for (int tri = 0; tri < 2; ++tri) {
    int u = 32 * w + 16 * tri + lr;
#pragma unroll
    for (int g = 0; g < 3; ++g) {
      int n = g * 256 + u;
      bias[tri][g] = brec[n];
#pragma unroll
      for (int k0 = 0; k0 < 6; ++k0)
        ufr[tri][g][k0] = *(const f32x4*)(Ut + (size_t)n * 256 + 32 * k0 + 8 * lg);
    }
  }
  // Opaque pin: keeps all 36 fragments (144 VGPRs) register-resident.
#pragma unroll
  for (int tri = 0; tri < 2; ++tri)
#pragma unroll
    for (int g = 0; g < 3; ++g)
#pragma unroll
      for (int k0 = 0; k0 < 6; ++k0)
        asm volatile("" : "+v"(ufr[tri][g][k0]));

  // h init (broadcast h0 across batch) into buffer 0
  float hprev[2][4];
#pragma unroll
  for (int tri = 0; tri < 2; ++tri) {
    int u = 32 * w + 16 * tri + lr;
    float hv = h0[u];
#pragma unroll
    for (int r = 0; r < 4; ++r) {
      hprev[tri][r] = hv;
      int b = 4 * lg + r;
      Hsm[0][b * STR + u] = f2bf(hv);
    }
  }

  // Prefetch xg(0)
  u16x4 xv[2][4];
#pragma unroll
  for (int tri = 0; tri < 2; ++tri) {
    int u = 32 * w + 16 * tri + lr;
#pragma unroll
    for (int r = 0; r < 4; ++r) {
      int b = 4 * lg + r;
      xv[tri][r] = *(const u16x4*)(xgp + ((size_t)b * TT) * 1024 + u * 4);
    }
  }
  wg_barrier_lds();

  for (int t = 0; t < TT; ++t) {
    const unsigned short* cur = &Hsm[t & 1][0];
    unsigned short* nxt = &Hsm[(t + 1) & 1][0];

    // Residual prefetch (window = MFMA phase)
    float ypref[2][4];
    if (resid) {
#pragma unroll
      for (int tri = 0; tri < 2; ++tri) {
        int u = 32 * w + 16 * tri + lr;
#pragma unroll
        for (int r = 0; r < 4; ++r) {
          int b = 4 * lg + r;
          ypref[tri][r] = y[((size_t)b * TT + t) * UU + u];
        }
      }
    }

    // rg = h @ U + b_rec (bias in acc init)
    f32x4 acc[2][3];
#pragma unroll
    for (int tri = 0; tri < 2; ++tri)
#pragma unroll
      for (int g = 0; g < 3; ++g) {
        float bv = bias[tri][g];
        acc[tri][g] = (f32x4){bv, bv, bv, bv};
      }
#pragma unroll
    for (int k0 = 0; k0 < 8; ++k0) {
      bf16x8 a = *(const bf16x8*)(&cur[lr * STR + 32 * k0 + 8 * lg]);
      if (k0 < 6) {
#pragma unroll
        for (int tri = 0; tri < 2; ++tri)
#pragma unroll
          for (int g = 0; g < 3; ++g)
            acc[tri][g] = __builtin_amdgcn_mfma_f32_16x16x32_bf16(
                a, __builtin_bit_cast(bf16x8, ufr[tri][g][k0]), acc[tri][g], 0, 0, 0);
      } else {
#pragma unroll
        for (int tri = 0; tri < 2; ++tri)
#pragma unroll
          for (int g = 0; g < 3; ++g) {
            int n = g * 256 + 32 * w + 16 * tri + lr;
            bf16x8 bfr = *(const bf16x8*)(&Utail[n * 72 + (k0 - 6) * 32 + 8 * lg]);
            acc[tri][g] = __builtin_amdgcn_mfma_f32_16x16x32_bf16(a, bfr, acc[tri][g], 0, 0, 0);
          }
      }
    }
    // NO barrier here: gate phase writes `nxt`, MFMA read `cur` (disjoint buffers).

    const int tn = (t + 1 < TT) ? t + 1 : t;  // prefetch target (capped; last discarded)
    // Gate math in registers; lane owns (b = 4*lg+r, u = 32w+16tri+lr)
#pragma unroll
    for (int tri = 0; tri < 2; ++tri) {
      int u = 32 * w + 16 * tri + lr;
#pragma unroll
      for (int r = 0; r < 4; ++r) {
        int b = 4 * lg + r;
        u16x4 xvv = xv[tri][r];
        // reload just-freed xv regs with xg(t+1): latency hides under barrier+next MFMA
        xv[tri][r] = *(const u16x4*)(xgp + ((size_t)b * TT + tn) * 1024 + u * 4);
        float xz = bf2f(xvv.x), xr = bf2f(xvv.y), xh = bf2f(xvv.z);
        float h = hprev[tri][r];
        float z = sigm(xz + acc[tri][0][r]);
        float rg = sigm(xr + acc[tri][1][r]);
        float hh = tanh_(xh + rg * acc[tri][2][r]);
        float cand = hh + z * (h - hh);
        float hnew = cand + ZONEOUT * (h - cand);
        hprev[tri][r] = hnew;
        nxt[b * STR + u] = f2bf(hnew);
        float ov = cand;
        if (resid) ov += ypref[tri][r];
        y[((size_t)b * TT + t) * UU + u] = ov;  // store never blocks (no vmcnt drain)
      }
    }
    wg_barrier_lds();  // nxt visible to all waves; vmem stays in flight
  }
}

extern "C" void kernel_launch(void* const* d_in, const int* in_sizes, int n_in,
                              void* d_out, int out_size, void* d_ws, size_t ws_size,
                              hipStream_t stream) {
  const float* x = (const float*)d_in[0];
  const float* W[3]  = {(const float*)d_in[1], (const float*)d_in[5], (const float*)d_in[9]};
  const float* Um[3] = {(const float*)d_in[2], (const float*)d_in[6], (const float*)d_in[10]};
  const float* bm[3] = {(const float*)d_in[3], (const float*)d_in[7], (const float*)d_in[11]};
  const float* h0m[3] = {(const float*)d_in[4], (const float*)d_in[8], (const float*)d_in[12]};
  const float* Wd = (const float*)d_in[13];
  const float* bd = (const float*)d_in[14];
  float* out = (float*)d_out;

  char* ws = (char*)d_ws;
  unsigned short* xgp = (unsigned short*)ws;  // [65536][256][4] bf16 = 134,217,728 B
  size_t off = (size_t)65536 * 1024 * 2;
  unsigned short* Ut[3];
  unsigned short* Wt[3];
  for (int l = 0; l < 3; ++l) { Ut[l] = (unsigned short*)(ws + off); off += (size_t)768 * 256 * 2; }
  for (int l = 0; l < 3; ++l) { Wt[l] = (unsigned short*)(ws + off); off += (size_t)768 * 256 * 2; }
  unsigned short* Wdt = (unsigned short*)(ws + off); off += (size_t)256 * 256 * 2;

  const int tgrid = (768 * 256 + 255) / 256;
  for (int l = 0; l < 3; ++l) {
    hipLaunchKernelGGL(transpose_cast_kernel, dim3(tgrid), dim3(256), 0, stream, Um[l], Ut[l], 256, 768);
    hipLaunchKernelGGL(transpose_cast_kernel, dim3(tgrid), dim3(256), 0, stream, W[l], Wt[l], 256, 768);
  }
  hipLaunchKernelGGL(transpose_cast_kernel, dim3((256 * 256 + 255) / 256), dim3(256), 0, stream,
                     Wd, Wdt, 256, 256);

  for (int l = 0; l < 3; ++l) {
    const float* in_l = (l == 0) ? x : out;
    hipLaunchKernelGGL(gates_gemm_kernel, dim3(1024, 12), dim3(256), 0, stream,
                       in_l, Wt[l], bm[l], xgp);
    hipLaunchKernelGGL(gru_scan_kernel, dim3(1), dim3(512), 0, stream,
                       xgp, Ut[l], bm[l] + 768, h0m[l], out, l ? 1 : 0);
  }
  hipLaunchKernelGGL(head_gemm_kernel, dim3(1024), dim3(256), 0, stream, out, Wdt, bd);
}